// Round 1
// baseline (258.057 us; speedup 1.0000x reference)
//
#include <hip/hip_runtime.h>
#include <hip/hip_bf16.h>
#include <string.h>

#define B_ 8
#define N_ 50000
#define F_ 32
#define S_ 16
#define O_ 64
#define K_ (F_ * S_)            // 512
#define XELEMS (B_ * N_ * F_)   // 12.8M
#define TPB (N_ / 16)           // 3125 tiles per batch
#define BPB 196                 // blocks per batch (196*16 = 3136 >= 3125)

typedef __attribute__((ext_vector_type(8))) short bf16x8;
typedef __attribute__((ext_vector_type(4))) float f32x4;
typedef __attribute__((ext_vector_type(4))) int int4v;

union bfpack { bf16x8 v; __hip_bfloat16 h[8]; };

// ---- Prepass: W -> bf16 fragment-swizzled (64 KB) + x -> bf16 rows (25.6 MB) ----
// Wb[((kt*4 + quad)*64 + o)*8 + j] = bf16(W[o*512 + kt*32 + quad*8 + j])
__global__ __launch_bounds__(256) void prep_kernel(const float* __restrict__ W,
                                                   unsigned short* __restrict__ Wb,
                                                   const float* __restrict__ x,
                                                   unsigned short* __restrict__ xb) {
    int bid = blockIdx.x;
    if (bid < 128) {
        int i = bid * 256 + threadIdx.x; // [0, 32768)
        int j = i & 7;
        int o = (i >> 3) & 63;
        int qk = i >> 9;
        int quad = qk & 3;
        int kt = qk >> 2;
        __hip_bfloat16 h = __float2bfloat16(W[o * K_ + kt * 32 + quad * 8 + j]);
        unsigned short u; memcpy(&u, &h, 2);
        Wb[i] = u;
    } else {
        int i = (bid - 128) * 256 + threadIdx.x; // [0, 1.6M) groups of 8
        if (i < XELEMS / 8) {
            size_t base = (size_t)i * 8;
            f32x4 a = __builtin_nontemporal_load((const f32x4*)(x + base));
            f32x4 b = __builtin_nontemporal_load((const f32x4*)(x + base + 4));
            bfpack p;
            p.h[0] = __float2bfloat16(a[0]); p.h[1] = __float2bfloat16(a[1]);
            p.h[2] = __float2bfloat16(a[2]); p.h[3] = __float2bfloat16(a[3]);
            p.h[4] = __float2bfloat16(b[0]); p.h[5] = __float2bfloat16(b[1]);
            p.h[6] = __float2bfloat16(b[2]); p.h[7] = __float2bfloat16(b[3]);
            __builtin_nontemporal_store(p.v, (bf16x8*)(xb + base));
        }
    }
}

// ---- Main kernel: bf16 gathered GEMM, batch<->XCD partitioned, deep gather pipeline ----
// Block i works ONLY on batch (i & 7). Blocks round-robin to XCDs (i % 8),
// so each XCD's L2 sees a single 3.2 MB bf16 batch slice (fits 4 MB L2).
// adj loads and out stores are non-temporal so the streams don't evict xb from L2.
// Per kt4 group: ALL 16 gathers issued before any MFMA; next adj prefetched
// before the MFMA phase. __launch_bounds__(256,2) -> VGPR cap 256 so the
// compiler keeps the hoisted (high-MLP) schedule.
__global__ __launch_bounds__(256, 2) void spiral_kernel(
        const unsigned short* __restrict__ xb, const int* __restrict__ adj,
        const unsigned short* __restrict__ Wb, const float* __restrict__ bias,
        float* __restrict__ out) {
    const int lane = threadIdx.x & 63;
    const int wv   = threadIdx.x >> 6;
    const int m16  = lane & 15;
    const int quad = lane >> 4;

    const int b  = blockIdx.x & 7;   // batch == intended XCD
    const int jb = blockIdx.x >> 3;  // 0..195 block-within-batch
    const int tib0 = (jb * 4 + wv) * 4;

    int rowbase[4]; // b*N + n0 (n0 = tile start vertex within batch)
    int nn[4];
#pragma unroll
    for (int vt = 0; vt < 4; ++vt) {
        int t = tib0 + vt;
        if (t >= TPB) t = TPB - 1; // clamp within batch: duplicate identical stores, benign
        nn[vt] = t * 16;
        rowbase[vt] = b * N_ + t * 16;
    }
    const size_t xbase = (size_t)b * N_ * F_;

    // Preload adj (kt4 = 0) before anything else so the latency overlaps acc init.
    int4v ajc[4];
#pragma unroll
    for (int vt = 0; vt < 4; ++vt)
        ajc[vt] = __builtin_nontemporal_load(
            (const int4v*)(adj + (size_t)(rowbase[vt] + m16) * S_));

    f32x4 acc[4][4];
#pragma unroll
    for (int vt = 0; vt < 4; ++vt)
#pragma unroll
        for (int nt = 0; nt < 4; ++nt)
            acc[vt][nt] = (f32x4){0.f, 0.f, 0.f, 0.f};

#define DO_Q(QI, XF)                                                                       \
    do {                                                                                   \
        const int kt_ = kt4 * 4 + (QI);                                                    \
        bf16x8 wf0 = *(const bf16x8*)(Wb + (size_t)((kt_ * 4 + quad) * 64 +  0 + m16) * 8);\
        bf16x8 wf1 = *(const bf16x8*)(Wb + (size_t)((kt_ * 4 + quad) * 64 + 16 + m16) * 8);\
        bf16x8 wf2 = *(const bf16x8*)(Wb + (size_t)((kt_ * 4 + quad) * 64 + 32 + m16) * 8);\
        bf16x8 wf3 = *(const bf16x8*)(Wb + (size_t)((kt_ * 4 + quad) * 64 + 48 + m16) * 8);\
        _Pragma("unroll")                                                                  \
        for (int vt = 0; vt < 4; ++vt) {                                                   \
            acc[vt][0] = __builtin_amdgcn_mfma_f32_16x16x32_bf16(wf0, XF[vt], acc[vt][0], 0, 0, 0); \
            acc[vt][1] = __builtin_amdgcn_mfma_f32_16x16x32_bf16(wf1, XF[vt], acc[vt][1], 0, 0, 0); \
            acc[vt][2] = __builtin_amdgcn_mfma_f32_16x16x32_bf16(wf2, XF[vt], acc[vt][2], 0, 0, 0); \
            acc[vt][3] = __builtin_amdgcn_mfma_f32_16x16x32_bf16(wf3, XF[vt], acc[vt][3], 0, 0, 0); \
        }                                                                                  \
    } while (0)

#pragma unroll
    for (int kt4 = 0; kt4 < 4; ++kt4) {
        // Issue ALL 16 gathers for this kt4 group up front (16 x dwordx4 in flight).
        bf16x8 xf0[4], xf1[4], xf2[4], xf3[4];
#pragma unroll
        for (int vt = 0; vt < 4; ++vt) {
            xf0[vt] = *(const bf16x8*)(xb + xbase + (size_t)ajc[vt].x * F_ + quad * 8);
            xf1[vt] = *(const bf16x8*)(xb + xbase + (size_t)ajc[vt].y * F_ + quad * 8);
            xf2[vt] = *(const bf16x8*)(xb + xbase + (size_t)ajc[vt].z * F_ + quad * 8);
            xf3[vt] = *(const bf16x8*)(xb + xbase + (size_t)ajc[vt].w * F_ + quad * 8);
        }
        // Prefetch next kt4's adj while gathers are in flight / MFMAs run.
        if (kt4 < 3) {
            int4v ajn[4];
#pragma unroll
            for (int vt = 0; vt < 4; ++vt)
                ajn[vt] = __builtin_nontemporal_load(
                    (const int4v*)(adj + (size_t)(rowbase[vt] + m16) * S_ + (kt4 + 1) * 4));
            DO_Q(0, xf0);
            DO_Q(1, xf1);
            DO_Q(2, xf2);
            DO_Q(3, xf3);
#pragma unroll
            for (int vt = 0; vt < 4; ++vt) ajc[vt] = ajn[vt];
        } else {
            DO_Q(0, xf0);
            DO_Q(1, xf1);
            DO_Q(2, xf2);
            DO_Q(3, xf3);
        }
    }
#undef DO_Q

    // Epilogue. D layout: col = lane&15 = vertex, row = quad*4 + r = o within nt-tile.
    // Lane holds 4 consecutive o's for one vertex -> float4 non-temporal stores.
#pragma unroll
    for (int vt = 0; vt < 4; ++vt) {
        const int n = nn[vt] + m16;
        const bool zero = (n == N_ - 1);
        float* orow = out + (size_t)(rowbase[vt] + m16) * O_ + quad * 4;
#pragma unroll
        for (int nt = 0; nt < 4; ++nt) {
            f32x4 bv = *(const f32x4*)(bias + nt * 16 + quad * 4);
            f32x4 v;
#pragma unroll
            for (int r = 0; r < 4; ++r) {
                float t = acc[vt][nt][r] + bv[r];
                t = t > 0.f ? t : (__expf(t) - 1.f); // ELU alpha=1
                v[r] = zero ? 0.f : t;
            }
            __builtin_nontemporal_store(v, (f32x4*)(orow + nt * 16));
        }
    }
}

// ---- Fallback (ws too small): fp32-gather kernel ----
__global__ __launch_bounds__(256) void wconv_kernel(const float* __restrict__ W,
                                                    unsigned short* __restrict__ Wb) {
    int i = blockIdx.x * 256 + threadIdx.x;
    if (i < O_ * K_) {
        int j = i & 7, o = (i >> 3) & 63, qk = i >> 9;
        int quad = qk & 3, kt = qk >> 2;
        __hip_bfloat16 h = __float2bfloat16(W[o * K_ + kt * 32 + quad * 8 + j]);
        unsigned short u; memcpy(&u, &h, 2);
        Wb[i] = u;
    }
}

__global__ __launch_bounds__(256) void spiral_f32_kernel(
        const float* __restrict__ x, const int* __restrict__ adj,
        const unsigned short* __restrict__ Wb, const float* __restrict__ bias,
        float* __restrict__ out) {
    const int lane = threadIdx.x & 63;
    const int wv = threadIdx.x >> 6;
    const int m16 = lane & 15, quad = lane >> 4;
    const int b  = blockIdx.x & 7;
    const int jb = blockIdx.x >> 3;
    const int tib0 = (jb * 4 + wv) * 4;
    int rowbase[4], nn[4];
#pragma unroll
    for (int vt = 0; vt < 4; ++vt) {
        int t = tib0 + vt;
        if (t >= TPB) t = TPB - 1;
        nn[vt] = t * 16;
        rowbase[vt] = b * N_ + t * 16;
    }
    f32x4 acc[4][4];
#pragma unroll
    for (int vt = 0; vt < 4; ++vt)
#pragma unroll
        for (int nt = 0; nt < 4; ++nt) acc[vt][nt] = (f32x4){0.f,0.f,0.f,0.f};
    for (int kt = 0; kt < 16; ++kt) {
        bf16x8 wf[4];
#pragma unroll
        for (int nt = 0; nt < 4; ++nt)
            wf[nt] = *(const bf16x8*)(Wb + (size_t)((kt * 4 + quad) * 64 + nt * 16 + m16) * 8);
#pragma unroll
        for (int vt = 0; vt < 4; ++vt) {
            int a = adj[(size_t)(rowbase[vt] + m16) * S_ + kt];
            const float* xr = x + ((size_t)b * N_ + a) * F_ + quad * 8;
            f32x4 x0 = *(const f32x4*)xr;
            f32x4 x1 = *(const f32x4*)(xr + 4);
            bfpack af;
            af.h[0]=__float2bfloat16(x0[0]); af.h[1]=__float2bfloat16(x0[1]);
            af.h[2]=__float2bfloat16(x0[2]); af.h[3]=__float2bfloat16(x0[3]);
            af.h[4]=__float2bfloat16(x1[0]); af.h[5]=__float2bfloat16(x1[1]);
            af.h[6]=__float2bfloat16(x1[2]); af.h[7]=__float2bfloat16(x1[3]);
#pragma unroll
            for (int nt = 0; nt < 4; ++nt)
                acc[vt][nt] = __builtin_amdgcn_mfma_f32_16x16x32_bf16(wf[nt], af.v, acc[vt][nt], 0, 0, 0);
        }
    }
#pragma unroll
    for (int vt = 0; vt < 4; ++vt) {
        const int n = nn[vt] + m16;
        const bool zero = (n == N_ - 1);
        float* orow = out + (size_t)(rowbase[vt] + m16) * O_ + quad * 4;
#pragma unroll
        for (int nt = 0; nt < 4; ++nt) {
            f32x4 bv = *(const f32x4*)(bias + nt * 16 + quad * 4);
            f32x4 v;
#pragma unroll
            for (int r = 0; r < 4; ++r) {
                float t = acc[vt][nt][r] + bv[r];
                t = t > 0.f ? t : (__expf(t) - 1.f);
                v[r] = zero ? 0.f : t;
            }
            *(f32x4*)(orow + nt * 16) = v;
        }
    }
}

extern "C" void kernel_launch(void* const* d_in, const int* in_sizes, int n_in,
                              void* d_out, int out_size, void* d_ws, size_t ws_size,
                              hipStream_t stream) {
    const float* x    = (const float*)d_in[0];
    const int*   adj  = (const int*)d_in[1];
    const float* W    = (const float*)d_in[2];
    const float* bias = (const float*)d_in[3];
    float* out = (float*)d_out;

    const size_t wb_bytes = (size_t)O_ * K_ * 2;            // 64 KB
    const size_t xb_bytes = (size_t)XELEMS * 2;             // 25.6 MB
    unsigned short* Wb = (unsigned short*)d_ws;
    unsigned short* xb = (unsigned short*)((char*)d_ws + wb_bytes);

    const int grid_main = 8 * BPB; // 1568 blocks, batch = blockIdx % 8

    if (ws_size >= wb_bytes + xb_bytes) {
        int grid_prep = 128 + (XELEMS / 8 + 255) / 256; // 128 + 6250
        hipLaunchKernelGGL(prep_kernel, dim3(grid_prep), dim3(256), 0, stream, W, Wb, x, xb);
        hipLaunchKernelGGL(spiral_kernel, dim3(grid_main), dim3(256), 0, stream,
                           xb, adj, Wb, bias, out);
    } else {
        hipLaunchKernelGGL(wconv_kernel, dim3(128), dim3(256), 0, stream, W, Wb);
        hipLaunchKernelGGL(spiral_f32_kernel, dim3(grid_main), dim3(256), 0, stream,
                           x, adj, Wb, bias, out);
    }
}

// Round 2
// 251.242 us; speedup vs baseline: 1.0271x; 1.0271x over previous
//
#include <hip/hip_runtime.h>
#include <hip/hip_bf16.h>
#include <string.h>

#define B_ 8
#define N_ 50000
#define F_ 32
#define S_ 16
#define O_ 64
#define K_ (F_ * S_)            // 512
#define XELEMS (B_ * N_ * F_)   // 12.8M
#define TPB (N_ / 16)           // 3125 tiles per batch
#define VT_ 2                   // tiles per wave (was 4): halves AGPR acc -> 2x occupancy
#define BPB 391                 // blocks per batch (391 * 4 waves * 2 tiles = 3128 >= 3125)

typedef __attribute__((ext_vector_type(8))) short bf16x8;
typedef __attribute__((ext_vector_type(4))) float f32x4;
typedef __attribute__((ext_vector_type(4))) int int4v;

union bfpack { bf16x8 v; __hip_bfloat16 h[8]; };

// ---- Prepass: W -> bf16 fragment-swizzled (64 KB) + x -> bf16 rows (25.6 MB) ----
// Wb[((kt*4 + quad)*64 + o)*8 + j] = bf16(W[o*512 + kt*32 + quad*8 + j])
__global__ __launch_bounds__(256) void prep_kernel(const float* __restrict__ W,
                                                   unsigned short* __restrict__ Wb,
                                                   const float* __restrict__ x,
                                                   unsigned short* __restrict__ xb) {
    int bid = blockIdx.x;
    if (bid < 128) {
        int i = bid * 256 + threadIdx.x; // [0, 32768)
        int j = i & 7;
        int o = (i >> 3) & 63;
        int qk = i >> 9;
        int quad = qk & 3;
        int kt = qk >> 2;
        __hip_bfloat16 h = __float2bfloat16(W[o * K_ + kt * 32 + quad * 8 + j]);
        unsigned short u; memcpy(&u, &h, 2);
        Wb[i] = u;
    } else {
        int i = (bid - 128) * 256 + threadIdx.x; // [0, 1.6M) groups of 8
        if (i < XELEMS / 8) {
            size_t base = (size_t)i * 8;
            f32x4 a = __builtin_nontemporal_load((const f32x4*)(x + base));
            f32x4 b = __builtin_nontemporal_load((const f32x4*)(x + base + 4));
            bfpack p;
            p.h[0] = __float2bfloat16(a[0]); p.h[1] = __float2bfloat16(a[1]);
            p.h[2] = __float2bfloat16(a[2]); p.h[3] = __float2bfloat16(a[3]);
            p.h[4] = __float2bfloat16(b[0]); p.h[5] = __float2bfloat16(b[1]);
            p.h[6] = __float2bfloat16(b[2]); p.h[7] = __float2bfloat16(b[3]);
            *(bf16x8*)(xb + base) = p.v;
        }
    }
}

// ---- Main kernel: bf16 gathered GEMM, batch<->XCD partitioned ----
// Block i works ONLY on batch (i & 7). Blocks round-robin to XCDs (i % 8),
// so each XCD's L2 sees a single 3.2 MB bf16 batch slice (fits 4 MB L2).
// VT_=2 tiles/wave: acc = 2x4 f32x4 = 32 AGPRs (was 64). Total reg footprint
// ~100-110 -> quantizes to 128 -> 4 waves/SIMD (was 2). __launch_bounds__(256,4)
// enforces the 128-reg cap. Latency hiding comes from TLP (2x resident waves),
// not from compiler-hoisted loads (round-1 showed the compiler won't hold them).
__global__ __launch_bounds__(256, 4) void spiral_kernel(
        const unsigned short* __restrict__ xb, const int* __restrict__ adj,
        const unsigned short* __restrict__ Wb, const float* __restrict__ bias,
        float* __restrict__ out) {
    const int lane = threadIdx.x & 63;
    const int wv   = threadIdx.x >> 6;
    const int m16  = lane & 15;
    const int quad = lane >> 4;

    const int b  = blockIdx.x & 7;   // batch == intended XCD
    const int jb = blockIdx.x >> 3;  // 0..390 block-within-batch
    const int tib0 = (jb * 4 + wv) * VT_;

    int rowbase[VT_]; // b*N + n0 (n0 = tile start vertex within batch)
    int nn[VT_];
#pragma unroll
    for (int vt = 0; vt < VT_; ++vt) {
        int t = tib0 + vt;
        if (t >= TPB) t = TPB - 1; // clamp within batch: duplicate identical stores, benign
        nn[vt] = t * 16;
        rowbase[vt] = b * N_ + t * 16;
    }
    const size_t xbase = (size_t)b * N_ * F_;

    f32x4 acc[VT_][4];
#pragma unroll
    for (int vt = 0; vt < VT_; ++vt)
#pragma unroll
        for (int nt = 0; nt < 4; ++nt)
            acc[vt][nt] = (f32x4){0.f, 0.f, 0.f, 0.f};

#pragma unroll
    for (int kt4 = 0; kt4 < 4; ++kt4) {
        // adj rows: lane's vertex row = rowbase+m16; 4 kt's of neighbor ids at once.
        // Non-temporal: adj is a read-once stream, keep it out of L2 so the 3.2 MB
        // xb slice stays resident (round-1: this cut FETCH_SIZE by ~half).
        int4v aj[VT_];
#pragma unroll
        for (int vt = 0; vt < VT_; ++vt)
            aj[vt] = __builtin_nontemporal_load(
                (const int4v*)(adj + (size_t)(rowbase[vt] + m16) * S_ + kt4 * 4));

#pragma unroll
        for (int q = 0; q < 4; ++q) {
            const int kt = kt4 * 4 + q;
            bf16x8 xf[VT_];
#pragma unroll
            for (int vt = 0; vt < VT_; ++vt) {
                int a = ((const int*)&aj[vt])[q];
                xf[vt] = *(const bf16x8*)(xb + xbase + (size_t)a * F_ + quad * 8);
            }
            bf16x8 wf[4];
#pragma unroll
            for (int nt = 0; nt < 4; ++nt)
                wf[nt] = *(const bf16x8*)(Wb + (size_t)((kt * 4 + quad) * 64 + nt * 16 + m16) * 8);
#pragma unroll
            for (int vt = 0; vt < VT_; ++vt)
#pragma unroll
                for (int nt = 0; nt < 4; ++nt)
                    // A = W-tile (m = o_local), B = x-tile (n = vertex)
                    acc[vt][nt] = __builtin_amdgcn_mfma_f32_16x16x32_bf16(wf[nt], xf[vt], acc[vt][nt], 0, 0, 0);
        }
    }

    // Epilogue. D layout: col = lane&15 = vertex, row = quad*4 + r = o within nt-tile.
    // Lane holds 4 consecutive o's for one vertex -> float4 stores (cached: round-0
    // showed exact-size WRITE_SIZE; nt stores caused 1.35x write amplification).
#pragma unroll
    for (int vt = 0; vt < VT_; ++vt) {
        const int n = nn[vt] + m16;
        const bool zero = (n == N_ - 1);
        float* orow = out + (size_t)(rowbase[vt] + m16) * O_ + quad * 4;
#pragma unroll
        for (int nt = 0; nt < 4; ++nt) {
            f32x4 bv = *(const f32x4*)(bias + nt * 16 + quad * 4);
            f32x4 v;
#pragma unroll
            for (int r = 0; r < 4; ++r) {
                float t = acc[vt][nt][r] + bv[r];
                t = t > 0.f ? t : (__expf(t) - 1.f); // ELU alpha=1
                v[r] = zero ? 0.f : t;
            }
            *(f32x4*)(orow + nt * 16) = v;
        }
    }
}

// ---- Fallback (ws too small): fp32-gather kernel ----
__global__ __launch_bounds__(256) void wconv_kernel(const float* __restrict__ W,
                                                    unsigned short* __restrict__ Wb) {
    int i = blockIdx.x * 256 + threadIdx.x;
    if (i < O_ * K_) {
        int j = i & 7, o = (i >> 3) & 63, qk = i >> 9;
        int quad = qk & 3, kt = qk >> 2;
        __hip_bfloat16 h = __float2bfloat16(W[o * K_ + kt * 32 + quad * 8 + j]);
        unsigned short u; memcpy(&u, &h, 2);
        Wb[i] = u;
    }
}

__global__ __launch_bounds__(256) void spiral_f32_kernel(
        const float* __restrict__ x, const int* __restrict__ adj,
        const unsigned short* __restrict__ Wb, const float* __restrict__ bias,
        float* __restrict__ out) {
    const int lane = threadIdx.x & 63;
    const int wv = threadIdx.x >> 6;
    const int m16 = lane & 15, quad = lane >> 4;
    const int b  = blockIdx.x & 7;
    const int jb = blockIdx.x >> 3;
    const int tib0 = (jb * 4 + wv) * 4;
    int rowbase[4], nn[4];
#pragma unroll
    for (int vt = 0; vt < 4; ++vt) {
        int t = tib0 + vt;
        if (t >= TPB) t = TPB - 1;
        nn[vt] = t * 16;
        rowbase[vt] = b * N_ + t * 16;
    }
    f32x4 acc[4][4];
#pragma unroll
    for (int vt = 0; vt < 4; ++vt)
#pragma unroll
        for (int nt = 0; nt < 4; ++nt) acc[vt][nt] = (f32x4){0.f,0.f,0.f,0.f};
    for (int kt = 0; kt < 16; ++kt) {
        bf16x8 wf[4];
#pragma unroll
        for (int nt = 0; nt < 4; ++nt)
            wf[nt] = *(const bf16x8*)(Wb + (size_t)((kt * 4 + quad) * 64 + nt * 16 + m16) * 8);
#pragma unroll
        for (int vt = 0; vt < 4; ++vt) {
            int a = adj[(size_t)(rowbase[vt] + m16) * S_ + kt];
            const float* xr = x + ((size_t)b * N_ + a) * F_ + quad * 8;
            f32x4 x0 = *(const f32x4*)xr;
            f32x4 x1 = *(const f32x4*)(xr + 4);
            bfpack af;
            af.h[0]=__float2bfloat16(x0[0]); af.h[1]=__float2bfloat16(x0[1]);
            af.h[2]=__float2bfloat16(x0[2]); af.h[3]=__float2bfloat16(x0[3]);
            af.h[4]=__float2bfloat16(x1[0]); af.h[5]=__float2bfloat16(x1[1]);
            af.h[6]=__float2bfloat16(x1[2]); af.h[7]=__float2bfloat16(x1[3]);
#pragma unroll
            for (int nt = 0; nt < 4; ++nt)
                acc[vt][nt] = __builtin_amdgcn_mfma_f32_16x16x32_bf16(wf[nt], af.v, acc[vt][nt], 0, 0, 0);
        }
    }
#pragma unroll
    for (int vt = 0; vt < 4; ++vt) {
        const int n = nn[vt] + m16;
        const bool zero = (n == N_ - 1);
        float* orow = out + (size_t)(rowbase[vt] + m16) * O_ + quad * 4;
#pragma unroll
        for (int nt = 0; nt < 4; ++nt) {
            f32x4 bv = *(const f32x4*)(bias + nt * 16 + quad * 4);
            f32x4 v;
#pragma unroll
            for (int r = 0; r < 4; ++r) {
                float t = acc[vt][nt][r] + bv[r];
                t = t > 0.f ? t : (__expf(t) - 1.f);
                v[r] = zero ? 0.f : t;
            }
            *(f32x4*)(orow + nt * 16) = v;
        }
    }
}

extern "C" void kernel_launch(void* const* d_in, const int* in_sizes, int n_in,
                              void* d_out, int out_size, void* d_ws, size_t ws_size,
                              hipStream_t stream) {
    const float* x    = (const float*)d_in[0];
    const int*   adj  = (const int*)d_in[1];
    const float* W    = (const float*)d_in[2];
    const float* bias = (const float*)d_in[3];
    float* out = (float*)d_out;

    const size_t wb_bytes = (size_t)O_ * K_ * 2;            // 64 KB
    const size_t xb_bytes = (size_t)XELEMS * 2;             // 25.6 MB
    unsigned short* Wb = (unsigned short*)d_ws;
    unsigned short* xb = (unsigned short*)((char*)d_ws + wb_bytes);

    const int grid_main = 8 * BPB; // 3128 blocks, batch = blockIdx % 8

    if (ws_size >= wb_bytes + xb_bytes) {
        int grid_prep = 128 + (XELEMS / 8 + 255) / 256; // 128 + 6250
        hipLaunchKernelGGL(prep_kernel, dim3(grid_prep), dim3(256), 0, stream, W, Wb, x, xb);
        hipLaunchKernelGGL(spiral_kernel, dim3(grid_main), dim3(256), 0, stream,
                           xb, adj, Wb, bias, out);
    } else {
        hipLaunchKernelGGL(wconv_kernel, dim3(128), dim3(256), 0, stream, W, Wb);
        hipLaunchKernelGGL(spiral_f32_kernel, dim3(8 * 196), dim3(256), 0, stream,
                           x, adj, Wb, bias, out);
    }
}

// Round 3
// 248.312 us; speedup vs baseline: 1.0392x; 1.0118x over previous
//
#include <hip/hip_runtime.h>
#include <hip/hip_bf16.h>
#include <string.h>

#define B_ 8
#define N_ 50000
#define F_ 32
#define S_ 16
#define O_ 64
#define K_ (F_ * S_)            // 512
#define XELEMS (B_ * N_ * F_)   // 12.8M
#define TPB (N_ / 16)           // 3125 tiles per batch
#define BPB 196                 // blocks per batch (196*16 = 3136 >= 3125)
#define LDSTRIDE 68             // 64 + 4 pad floats: write/read phases both 2-way banks (free)

typedef __attribute__((ext_vector_type(8))) short bf16x8;
typedef __attribute__((ext_vector_type(4))) float f32x4;
typedef __attribute__((ext_vector_type(4))) int int4v;

union bfpack { bf16x8 v; __hip_bfloat16 h[8]; };

// ---- Prepass: W -> bf16 fragment-swizzled (64 KB) + x -> bf16 rows (25.6 MB) ----
// Wb[((kt*4 + quad)*64 + o)*8 + j] = bf16(W[o*512 + kt*32 + quad*8 + j])
__global__ __launch_bounds__(256) void prep_kernel(const float* __restrict__ W,
                                                   unsigned short* __restrict__ Wb,
                                                   const float* __restrict__ x,
                                                   unsigned short* __restrict__ xb) {
    int bid = blockIdx.x;
    if (bid < 128) {
        int i = bid * 256 + threadIdx.x; // [0, 32768)
        int j = i & 7;
        int o = (i >> 3) & 63;
        int qk = i >> 9;
        int quad = qk & 3;
        int kt = qk >> 2;
        __hip_bfloat16 h = __float2bfloat16(W[o * K_ + kt * 32 + quad * 8 + j]);
        unsigned short u; memcpy(&u, &h, 2);
        Wb[i] = u;
    } else {
        int i = (bid - 128) * 256 + threadIdx.x; // [0, 1.6M) groups of 8
        if (i < XELEMS / 8) {
            size_t base = (size_t)i * 8;
            f32x4 a = __builtin_nontemporal_load((const f32x4*)(x + base));
            f32x4 b = __builtin_nontemporal_load((const f32x4*)(x + base + 4));
            bfpack p;
            p.h[0] = __float2bfloat16(a[0]); p.h[1] = __float2bfloat16(a[1]);
            p.h[2] = __float2bfloat16(a[2]); p.h[3] = __float2bfloat16(a[3]);
            p.h[4] = __float2bfloat16(b[0]); p.h[5] = __float2bfloat16(b[1]);
            p.h[6] = __float2bfloat16(b[2]); p.h[7] = __float2bfloat16(b[3]);
            *(bf16x8*)(xb + base) = p.v;
        }
    }
}

// ---- Main kernel: bf16 gathered GEMM, batch<->XCD partitioned ----
// Round-0 structure (VT=4, fastest measured). Cache policy:
//  - adj: non-temporal (read-once stream, keep out of L2)            [-33 MB FETCH, r2]
//  - out: non-temporal via LDS-transposed epilogue so each store
//    instruction covers a contiguous aligned 1 KB per wave -> full-line
//    write-through, no amplification (r1's 16B/lane nt stores hit 1.36x)
//  - xb gathers + Wb: cached. The whole point: the 3.2 MB per-XCD xb
//    slice stays L2-resident because no stream sweeps L2 anymore.
__global__ __launch_bounds__(256) void spiral_kernel(
        const unsigned short* __restrict__ xb, const int* __restrict__ adj,
        const unsigned short* __restrict__ Wb, const float* __restrict__ bias,
        float* __restrict__ out) {
    const int lane = threadIdx.x & 63;
    const int wv   = threadIdx.x >> 6;
    const int m16  = lane & 15;
    const int quad = lane >> 4;

    const int b  = blockIdx.x & 7;   // batch == intended XCD
    const int jb = blockIdx.x >> 3;  // 0..195 block-within-batch
    const int tib0 = (jb * 4 + wv) * 4;

    __shared__ float ldsbuf[4][2][16][LDSTRIDE]; // [wave][vt-pair slot][vertex][o] = 34.8 KB

    int rowbase[4]; // b*N + n0 (n0 = tile start vertex within batch)
    int nn[4];
#pragma unroll
    for (int vt = 0; vt < 4; ++vt) {
        int t = tib0 + vt;
        if (t >= TPB) t = TPB - 1; // clamp within batch: duplicate identical stores, benign
        nn[vt] = t * 16;
        rowbase[vt] = b * N_ + t * 16;
    }
    const size_t xbase = (size_t)b * N_ * F_;

    f32x4 acc[4][4];
#pragma unroll
    for (int vt = 0; vt < 4; ++vt)
#pragma unroll
        for (int nt = 0; nt < 4; ++nt)
            acc[vt][nt] = (f32x4){0.f, 0.f, 0.f, 0.f};

#pragma unroll
    for (int kt4 = 0; kt4 < 4; ++kt4) {
        // adj rows: lane's vertex row = rowbase+m16; 4 kt's of neighbor ids at once
        int4v aj[4];
#pragma unroll
        for (int vt = 0; vt < 4; ++vt)
            aj[vt] = __builtin_nontemporal_load(
                (const int4v*)(adj + (size_t)(rowbase[vt] + m16) * S_ + kt4 * 4));

#pragma unroll
        for (int q = 0; q < 4; ++q) {
            const int kt = kt4 * 4 + q;
            bf16x8 xf[4];
#pragma unroll
            for (int vt = 0; vt < 4; ++vt) {
                int a = ((const int*)&aj[vt])[q];
                xf[vt] = *(const bf16x8*)(xb + xbase + (size_t)a * F_ + quad * 8);
            }
            bf16x8 wf[4];
#pragma unroll
            for (int nt = 0; nt < 4; ++nt)
                wf[nt] = *(const bf16x8*)(Wb + (size_t)((kt * 4 + quad) * 64 + nt * 16 + m16) * 8);
#pragma unroll
            for (int vt = 0; vt < 4; ++vt)
#pragma unroll
                for (int nt = 0; nt < 4; ++nt)
                    // A = W-tile (m = o_local), B = x-tile (n = vertex)
                    acc[vt][nt] = __builtin_amdgcn_mfma_f32_16x16x32_bf16(wf[nt], xf[vt], acc[vt][nt], 0, 0, 0);
        }
    }

    // Epilogue. D layout: col = lane&15 = vertex, row = quad*4 + r = o within nt-tile.
    // Stage each 16x64 tile through LDS so global nt stores are contiguous:
    // instruction i of a tile writes rows i*4..i*4+3 = aligned 1 KB per wave.
#pragma unroll
    for (int half = 0; half < 2; ++half) {
        if (half) __syncthreads(); // buffer reuse guard
#pragma unroll
        for (int vh = 0; vh < 2; ++vh) {
            const int vt = half * 2 + vh;
            const bool zero = (nn[vt] + m16 == N_ - 1);
#pragma unroll
            for (int nt = 0; nt < 4; ++nt) {
                f32x4 bv = *(const f32x4*)(bias + nt * 16 + quad * 4);
                f32x4 v;
#pragma unroll
                for (int r = 0; r < 4; ++r) {
                    float t = acc[vt][nt][r] + bv[r];
                    t = t > 0.f ? t : (__expf(t) - 1.f); // ELU alpha=1
                    v[r] = zero ? 0.f : t;
                }
                *(f32x4*)&ldsbuf[wv][vh][m16][nt * 16 + quad * 4] = v;
            }
        }
        __syncthreads();
#pragma unroll
        for (int vh = 0; vh < 2; ++vh) {
            const int vt = half * 2 + vh;
#pragma unroll
            for (int i = 0; i < 4; ++i) {
                f32x4 v = *(const f32x4*)&ldsbuf[wv][vh][i * 4 + (lane >> 4)][(lane & 15) * 4];
                __builtin_nontemporal_store(v,
                    (f32x4*)(out + (size_t)(rowbase[vt] + i * 4 + (lane >> 4)) * O_ + (lane & 15) * 4));
            }
        }
    }
}

// ---- Fallback (ws too small): fp32-gather kernel ----
__global__ __launch_bounds__(256) void wconv_kernel(const float* __restrict__ W,
                                                    unsigned short* __restrict__ Wb) {
    int i = blockIdx.x * 256 + threadIdx.x;
    if (i < O_ * K_) {
        int j = i & 7, o = (i >> 3) & 63, qk = i >> 9;
        int quad = qk & 3, kt = qk >> 2;
        __hip_bfloat16 h = __float2bfloat16(W[o * K_ + kt * 32 + quad * 8 + j]);
        unsigned short u; memcpy(&u, &h, 2);
        Wb[i] = u;
    }
}

__global__ __launch_bounds__(256) void spiral_f32_kernel(
        const float* __restrict__ x, const int* __restrict__ adj,
        const unsigned short* __restrict__ Wb, const float* __restrict__ bias,
        float* __restrict__ out) {
    const int lane = threadIdx.x & 63;
    const int wv = threadIdx.x >> 6;
    const int m16 = lane & 15, quad = lane >> 4;
    const int b  = blockIdx.x & 7;
    const int jb = blockIdx.x >> 3;
    const int tib0 = (jb * 4 + wv) * 4;
    int rowbase[4], nn[4];
#pragma unroll
    for (int vt = 0; vt < 4; ++vt) {
        int t = tib0 + vt;
        if (t >= TPB) t = TPB - 1;
        nn[vt] = t * 16;
        rowbase[vt] = b * N_ + t * 16;
    }
    f32x4 acc[4][4];
#pragma unroll
    for (int vt = 0; vt < 4; ++vt)
#pragma unroll
        for (int nt = 0; nt < 4; ++nt) acc[vt][nt] = (f32x4){0.f,0.f,0.f,0.f};
    for (int kt = 0; kt < 16; ++kt) {
        bf16x8 wf[4];
#pragma unroll
        for (int nt = 0; nt < 4; ++nt)
            wf[nt] = *(const bf16x8*)(Wb + (size_t)((kt * 4 + quad) * 64 + nt * 16 + m16) * 8);
#pragma unroll
        for (int vt = 0; vt < 4; ++vt) {
            int a = adj[(size_t)(rowbase[vt] + m16) * S_ + kt];
            const float* xr = x + ((size_t)b * N_ + a) * F_ + quad * 8;
            f32x4 x0 = *(const f32x4*)xr;
            f32x4 x1 = *(const f32x4*)(xr + 4);
            bfpack af;
            af.h[0]=__float2bfloat16(x0[0]); af.h[1]=__float2bfloat16(x0[1]);
            af.h[2]=__float2bfloat16(x0[2]); af.h[3]=__float2bfloat16(x0[3]);
            af.h[4]=__float2bfloat16(x1[0]); af.h[5]=__float2bfloat16(x1[1]);
            af.h[6]=__float2bfloat16(x1[2]); af.h[7]=__float2bfloat16(x1[3]);
#pragma unroll
            for (int nt = 0; nt < 4; ++nt)
                acc[vt][nt] = __builtin_amdgcn_mfma_f32_16x16x32_bf16(wf[nt], af.v, acc[vt][nt], 0, 0, 0);
        }
    }
#pragma unroll
    for (int vt = 0; vt < 4; ++vt) {
        const int n = nn[vt] + m16;
        const bool zero = (n == N_ - 1);
        float* orow = out + (size_t)(rowbase[vt] + m16) * O_ + quad * 4;
#pragma unroll
        for (int nt = 0; nt < 4; ++nt) {
            f32x4 bv = *(const f32x4*)(bias + nt * 16 + quad * 4);
            f32x4 v;
#pragma unroll
            for (int r = 0; r < 4; ++r) {
                float t = acc[vt][nt][r] + bv[r];
                t = t > 0.f ? t : (__expf(t) - 1.f);
                v[r] = zero ? 0.f : t;
            }
            *(f32x4*)(orow + nt * 16) = v;
        }
    }
}

extern "C" void kernel_launch(void* const* d_in, const int* in_sizes, int n_in,
                              void* d_out, int out_size, void* d_ws, size_t ws_size,
                              hipStream_t stream) {
    const float* x    = (const float*)d_in[0];
    const int*   adj  = (const int*)d_in[1];
    const float* W    = (const float*)d_in[2];
    const float* bias = (const float*)d_in[3];
    float* out = (float*)d_out;

    const size_t wb_bytes = (size_t)O_ * K_ * 2;            // 64 KB
    const size_t xb_bytes = (size_t)XELEMS * 2;             // 25.6 MB
    unsigned short* Wb = (unsigned short*)d_ws;
    unsigned short* xb = (unsigned short*)((char*)d_ws + wb_bytes);

    const int grid_main = 8 * BPB; // 1568 blocks, batch = blockIdx % 8

    if (ws_size >= wb_bytes + xb_bytes) {
        int grid_prep = 128 + (XELEMS / 8 + 255) / 256; // 128 + 6250
        hipLaunchKernelGGL(prep_kernel, dim3(grid_prep), dim3(256), 0, stream, W, Wb, x, xb);
        hipLaunchKernelGGL(spiral_kernel, dim3(grid_main), dim3(256), 0, stream,
                           xb, adj, Wb, bias, out);
    } else {
        hipLaunchKernelGGL(wconv_kernel, dim3(128), dim3(256), 0, stream, W, Wb);
        hipLaunchKernelGGL(spiral_f32_kernel, dim3(grid_main), dim3(256), 0, stream,
                           x, adj, Wb, bias, out);
    }
}

// Round 4
// 231.667 us; speedup vs baseline: 1.1139x; 1.0719x over previous
//
#include <hip/hip_runtime.h>
#include <hip/hip_bf16.h>
#include <string.h>

#define B_ 8
#define N_ 50000
#define F_ 32
#define S_ 16
#define O_ 64
#define K_ (F_ * S_)            // 512
#define XELEMS (B_ * N_ * F_)   // 12.8M
#define TPB (N_ / 16)           // 3125 tiles per batch
#define BPB 196                 // blocks per batch (196*16 = 3136 >= 3125)

typedef __attribute__((ext_vector_type(8))) short bf16x8;
typedef __attribute__((ext_vector_type(4))) float f32x4;
typedef __attribute__((ext_vector_type(4))) int int4v;

union bfpack { bf16x8 v; __hip_bfloat16 h[8]; };

// ---- Prepass: W -> bf16 fragment-swizzled (64 KB) + x -> bf16 rows (25.6 MB) ----
// Wb[((kt*4 + quad)*64 + o)*8 + j] = bf16(W[o*512 + kt*32 + quad*8 + j])
__global__ __launch_bounds__(256) void prep_kernel(const float* __restrict__ W,
                                                   unsigned short* __restrict__ Wb,
                                                   const float* __restrict__ x,
                                                   unsigned short* __restrict__ xb) {
    int bid = blockIdx.x;
    if (bid < 128) {
        int i = bid * 256 + threadIdx.x; // [0, 32768)
        int j = i & 7;
        int o = (i >> 3) & 63;
        int qk = i >> 9;
        int quad = qk & 3;
        int kt = qk >> 2;
        __hip_bfloat16 h = __float2bfloat16(W[o * K_ + kt * 32 + quad * 8 + j]);
        unsigned short u; memcpy(&u, &h, 2);
        Wb[i] = u;
    } else {
        int i = (bid - 128) * 256 + threadIdx.x; // [0, 1.6M) groups of 8
        if (i < XELEMS / 8) {
            size_t base = (size_t)i * 8;
            f32x4 a = __builtin_nontemporal_load((const f32x4*)(x + base));
            f32x4 b = __builtin_nontemporal_load((const f32x4*)(x + base + 4));
            bfpack p;
            p.h[0] = __float2bfloat16(a[0]); p.h[1] = __float2bfloat16(a[1]);
            p.h[2] = __float2bfloat16(a[2]); p.h[3] = __float2bfloat16(a[3]);
            p.h[4] = __float2bfloat16(b[0]); p.h[5] = __float2bfloat16(b[1]);
            p.h[6] = __float2bfloat16(b[2]); p.h[7] = __float2bfloat16(b[3]);
            *(bf16x8*)(xb + base) = p.v;
        }
    }
}

// ---- Main kernel: LDS-DMA deep-pipelined gathered GEMM ----
// r0 structure (VT=4, 4 waves, batch<->XCD partition, cached epilogue stores),
// but the x-row gathers go through __builtin_amdgcn_global_load_lds into a
// per-wave 4-slot ring (4 KB/slot). LDS-DMA needs no destination VGPRs, so
// pipeline depth is structural: 3 kt-chunks (12 gathers) + 3 W groups (12
// loads) in flight per wave, enforced with pinned issue order
// (sched_barrier(0) fences) and counted s_waitcnt vmcnt(24) (tail 16/8/0).
// Ring is wave-private -> zero barriers in the whole kernel.
__global__ __launch_bounds__(256, 2) void spiral_kernel(
        const unsigned short* __restrict__ xb, const int* __restrict__ adj,
        const unsigned short* __restrict__ Wb, const float* __restrict__ bias,
        float* __restrict__ out) {
    const int lane = threadIdx.x & 63;
    const int wv   = threadIdx.x >> 6;
    const int m16  = lane & 15;
    const int quad = lane >> 4;

    const int b  = blockIdx.x & 7;   // batch == intended XCD
    const int jb = blockIdx.x >> 3;  // 0..195 block-within-batch
    const int tib0 = (jb * 4 + wv) * 4;

    // [wave][ring slot][vt][1 KB]: lane deposits its 16 B at +lane*16. 64 KB.
    __shared__ __align__(16) unsigned char ring[4][4][4][1024];

    int rowbase[4]; // b*N + n0 (n0 = tile start vertex within batch)
    int nn[4];
#pragma unroll
    for (int vt = 0; vt < 4; ++vt) {
        int t = tib0 + vt;
        if (t >= TPB) t = TPB - 1; // clamp within batch: duplicate identical stores, benign
        nn[vt] = t * 16;
        rowbase[vt] = b * N_ + t * 16;
    }
    const size_t xbase = (size_t)b * N_ * F_;

    // All adj up front (nt: read-once stream). 16 x int4 = 64 VGPRs.
    int4v aj_all[4][4]; // [vt][kt4]
#pragma unroll
    for (int vt = 0; vt < 4; ++vt)
#pragma unroll
        for (int kt4 = 0; kt4 < 4; ++kt4)
            aj_all[vt][kt4] = __builtin_nontemporal_load(
                (const int4v*)(adj + (size_t)(rowbase[vt] + m16) * S_ + kt4 * 4));

    f32x4 acc[4][4];
#pragma unroll
    for (int vt = 0; vt < 4; ++vt)
#pragma unroll
        for (int nt = 0; nt < 4; ++nt)
            acc[vt][nt] = (f32x4){0.f, 0.f, 0.f, 0.f};

    bf16x8 wfp[4][4]; // W fragment pipeline: [ring slot][nt], all indices static

    // Issue gathers for kt = g_ into ring slot g_&3 (4 LDS-DMA, one per vt).
#define GATHER_ISSUE(g_)                                                                   \
    do {                                                                                   \
        if ((g_) < 16) {                                                                   \
            const int kt4_ = (g_) >> 2, q_ = (g_) & 3;                                     \
            _Pragma("unroll")                                                              \
            for (int vt = 0; vt < 4; ++vt) {                                               \
                int a_ = aj_all[vt][kt4_][q_];                                             \
                const unsigned short* src_ = xb + xbase + (size_t)a_ * F_ + quad * 8;      \
                __builtin_amdgcn_global_load_lds(                                          \
                    (const __attribute__((address_space(1))) void*)src_,                   \
                    (__attribute__((address_space(3))) void*)&ring[wv][(g_) & 3][vt][0],   \
                    16, 0, 0);                                                             \
            }                                                                              \
        }                                                                                  \
    } while (0)

#define LOAD_W(g_)                                                                         \
    do {                                                                                   \
        if ((g_) < 16) {                                                                   \
            _Pragma("unroll")                                                              \
            for (int nt = 0; nt < 4; ++nt)                                                 \
                wfp[(g_) & 3][nt] = *(const bf16x8*)(                                      \
                    Wb + (size_t)(((g_) * 4 + quad) * 64 + nt * 16 + m16) * 8);            \
        }                                                                                  \
    } while (0)

#define SB __builtin_amdgcn_sched_barrier(0)

    // Prologue: FIFO = C0 W0 C1 W1 C2 W2 (24 vmem in flight; leftover adj
    // loads ahead of them drain under the same counted waits).
    GATHER_ISSUE(0); SB; LOAD_W(0); SB;
    GATHER_ISSUE(1); SB; LOAD_W(1); SB;
    GATHER_ISSUE(2); SB; LOAD_W(2); SB;

#pragma unroll
    for (int g = 0; g < 16; ++g) {
        // Issue region: C_{g+3} then W_{g+3} (keeps FIFO pattern ...C W C W...).
        GATHER_ISSUE(g + 3); SB;
        LOAD_W(g + 3); SB;
        // Counted wait: drain C_g + W_g, keep the 3 newer C/W groups in flight.
        if (g < 13)       asm volatile("s_waitcnt vmcnt(24)" ::: "memory");
        else if (g == 13) asm volatile("s_waitcnt vmcnt(16)" ::: "memory");
        else if (g == 14) asm volatile("s_waitcnt vmcnt(8)"  ::: "memory");
        else              asm volatile("s_waitcnt vmcnt(0)"  ::: "memory");
        SB;
        // Consume slot g&3: each lane reads back its own 16 B per vt.
        bf16x8 xf[4];
#pragma unroll
        for (int vt = 0; vt < 4; ++vt)
            xf[vt] = *(const bf16x8*)&ring[wv][g & 3][vt][(size_t)lane * 16];
#pragma unroll
        for (int vt = 0; vt < 4; ++vt)
#pragma unroll
            for (int nt = 0; nt < 4; ++nt)
                // A = W-tile (m = o_local), B = x-tile (n = vertex)
                acc[vt][nt] = __builtin_amdgcn_mfma_f32_16x16x32_bf16(wfp[g & 3][nt], xf[vt], acc[vt][nt], 0, 0, 0);
        SB;
    }
#undef GATHER_ISSUE
#undef LOAD_W
#undef SB

    // Epilogue (r0 verbatim: cached stores, WRITE_SIZE was exact at 101 MB).
    // D layout: col = lane&15 = vertex, row = quad*4 + r = o within nt-tile.
#pragma unroll
    for (int vt = 0; vt < 4; ++vt) {
        const int n = nn[vt] + m16;
        const bool zero = (n == N_ - 1);
        float* orow = out + (size_t)(rowbase[vt] + m16) * O_ + quad * 4;
#pragma unroll
        for (int nt = 0; nt < 4; ++nt) {
            f32x4 bv = *(const f32x4*)(bias + nt * 16 + quad * 4);
            f32x4 v;
#pragma unroll
            for (int r = 0; r < 4; ++r) {
                float t = acc[vt][nt][r] + bv[r];
                t = t > 0.f ? t : (__expf(t) - 1.f); // ELU alpha=1
                v[r] = zero ? 0.f : t;
            }
            *(f32x4*)(orow + nt * 16) = v;
        }
    }
}

// ---- Fallback (ws too small): fp32-gather kernel ----
__global__ __launch_bounds__(256) void wconv_kernel(const float* __restrict__ W,
                                                    unsigned short* __restrict__ Wb) {
    int i = blockIdx.x * 256 + threadIdx.x;
    if (i < O_ * K_) {
        int j = i & 7, o = (i >> 3) & 63, qk = i >> 9;
        int quad = qk & 3, kt = qk >> 2;
        __hip_bfloat16 h = __float2bfloat16(W[o * K_ + kt * 32 + quad * 8 + j]);
        unsigned short u; memcpy(&u, &h, 2);
        Wb[i] = u;
    }
}

__global__ __launch_bounds__(256) void spiral_f32_kernel(
        const float* __restrict__ x, const int* __restrict__ adj,
        const unsigned short* __restrict__ Wb, const float* __restrict__ bias,
        float* __restrict__ out) {
    const int lane = threadIdx.x & 63;
    const int wv = threadIdx.x >> 6;
    const int m16 = lane & 15, quad = lane >> 4;
    const int b  = blockIdx.x & 7;
    const int jb = blockIdx.x >> 3;
    const int tib0 = (jb * 4 + wv) * 4;
    int rowbase[4], nn[4];
#pragma unroll
    for (int vt = 0; vt < 4; ++vt) {
        int t = tib0 + vt;
        if (t >= TPB) t = TPB - 1;
        nn[vt] = t * 16;
        rowbase[vt] = b * N_ + t * 16;
    }
    f32x4 acc[4][4];
#pragma unroll
    for (int vt = 0; vt < 4; ++vt)
#pragma unroll
        for (int nt = 0; nt < 4; ++nt) acc[vt][nt] = (f32x4){0.f,0.f,0.f,0.f};
    for (int kt = 0; kt < 16; ++kt) {
        bf16x8 wf[4];
#pragma unroll
        for (int nt = 0; nt < 4; ++nt)
            wf[nt] = *(const bf16x8*)(Wb + (size_t)((kt * 4 + quad) * 64 + nt * 16 + m16) * 8);
#pragma unroll
        for (int vt = 0; vt < 4; ++vt) {
            int a = adj[(size_t)(rowbase[vt] + m16) * S_ + kt];
            const float* xr = x + ((size_t)b * N_ + a) * F_ + quad * 8;
            f32x4 x0 = *(const f32x4*)xr;
            f32x4 x1 = *(const f32x4*)(xr + 4);
            bfpack af;
            af.h[0]=__float2bfloat16(x0[0]); af.h[1]=__float2bfloat16(x0[1]);
            af.h[2]=__float2bfloat16(x0[2]); af.h[3]=__float2bfloat16(x0[3]);
            af.h[4]=__float2bfloat16(x1[0]); af.h[5]=__float2bfloat16(x1[1]);
            af.h[6]=__float2bfloat16(x1[2]); af.h[7]=__float2bfloat16(x1[3]);
#pragma unroll
            for (int nt = 0; nt < 4; ++nt)
                acc[vt][nt] = __builtin_amdgcn_mfma_f32_16x16x32_bf16(wf[nt], af.v, acc[vt][nt], 0, 0, 0);
        }
    }
#pragma unroll
    for (int vt = 0; vt < 4; ++vt) {
        const int n = nn[vt] + m16;
        const bool zero = (n == N_ - 1);
        float* orow = out + (size_t)(rowbase[vt] + m16) * O_ + quad * 4;
#pragma unroll
        for (int nt = 0; nt < 4; ++nt) {
            f32x4 bv = *(const f32x4*)(bias + nt * 16 + quad * 4);
            f32x4 v;
#pragma unroll
            for (int r = 0; r < 4; ++r) {
                float t = acc[vt][nt][r] + bv[r];
                t = t > 0.f ? t : (__expf(t) - 1.f);
                v[r] = zero ? 0.f : t;
            }
            *(f32x4*)(orow + nt * 16) = v;
        }
    }
}

extern "C" void kernel_launch(void* const* d_in, const int* in_sizes, int n_in,
                              void* d_out, int out_size, void* d_ws, size_t ws_size,
                              hipStream_t stream) {
    const float* x    = (const float*)d_in[0];
    const int*   adj  = (const int*)d_in[1];
    const float* W    = (const float*)d_in[2];
    const float* bias = (const float*)d_in[3];
    float* out = (float*)d_out;

    const size_t wb_bytes = (size_t)O_ * K_ * 2;            // 64 KB
    const size_t xb_bytes = (size_t)XELEMS * 2;             // 25.6 MB
    unsigned short* Wb = (unsigned short*)d_ws;
    unsigned short* xb = (unsigned short*)((char*)d_ws + wb_bytes);

    const int grid_main = 8 * BPB; // 1568 blocks, batch = blockIdx % 8

    if (ws_size >= wb_bytes + xb_bytes) {
        int grid_prep = 128 + (XELEMS / 8 + 255) / 256; // 128 + 6250
        hipLaunchKernelGGL(prep_kernel, dim3(grid_prep), dim3(256), 0, stream, W, Wb, x, xb);
        hipLaunchKernelGGL(spiral_kernel, dim3(grid_main), dim3(256), 0, stream,
                           xb, adj, Wb, bias, out);
    } else {
        hipLaunchKernelGGL(wconv_kernel, dim3(128), dim3(256), 0, stream, W, Wb);
        hipLaunchKernelGGL(spiral_f32_kernel, dim3(grid_main), dim3(256), 0, stream,
                           x, adj, Wb, bias, out);
    }
}